// Round 6
// baseline (354.119 us; speedup 1.0000x reference)
//
#include <hip/hip_runtime.h>
#include <hip/hip_bf16.h>
#include <math.h>

// IntentionHeads R14: barrier-free layer 1 — A-frags direct from global.
//   Ledger: R11 (prefetch depth) null, R12 (lgkm-only barriers) null,
//   R13 (fast erf, -12% VALUBusy) only -6us. Matches learn_hip m233:
//   the 2-phase {stage, wait, barrier} structure itself costs ~70% and
//   no single-piece fix inside it shows a delta. So: remove the structure.
// R14 change (single structural variable):
//   - NO LDS X staging, NO K-loop barriers. Each wave loads its MFMA
//     A-fragments straight from global: rows i*16+l16, cols quad*8
//     (8 x global_load_dwordx4 per iter, literal imm offsets), converts
//     in-register (same pkrne RNE -> identical bits), MFMAs. The 64x32
//     per-iter slice is read 4x (once per wave) but stays L1/L2-resident
//     (XCD pairing keeps X tile in L2) -> overlappable cache BW, not
//     critical-path latency. Waves free-run; TLP hides everything.
//   - ONE barrier in the whole kernel (H handoff to layer 2).
//   - __launch_bounds__(256,4): force arch VGPR <= 64 (+64 acc = 128)
//     to restore 4 blocks/CU (R13 slipped to 68 VGPR / 3 blocks).
//   - Everything else identical to R13: fast erf, XCD swizzle, H layout,
//     layer 2, epilogue, numerics/op order (absmax must stay 0.015625).

#define TOKENS 65536
#define DIM    512
#define HID    256
#define HSTR   264   // H row stride in bf16 (256 + 8 pad, 16B mult)

using short8 = __attribute__((ext_vector_type(8))) short;  // 8 x bf16
using f32x4  = __attribute__((ext_vector_type(4))) float;

// packed RNE f32->bf16 pair (v_perm byte-pack)
__device__ __forceinline__ unsigned int pkrne(float a, float b) {
    unsigned int ua = __float_as_uint(a);
    unsigned int ub = __float_as_uint(b);
    ua += 0x7FFFu + ((ua >> 16) & 1u);
    ub += 0x7FFFu + ((ub >> 16) & 1u);
    return __builtin_amdgcn_perm(ub, ua, 0x07060302u);  // [ua.hi16, ub.hi16]
}

__device__ __forceinline__ uint2 cvt4(f32x4 v) {
    return make_uint2(pkrne(v[0], v[1]), pkrne(v[2], v[3]));
}

__device__ __forceinline__ __hip_bfloat16 bf16rne(float x) {
    unsigned int u = __float_as_uint(x);
    u += 0x7FFFu + ((u >> 16) & 1u);
    unsigned short hs = (unsigned short)(u >> 16);
    return *(__hip_bfloat16*)&hs;
}

__device__ __forceinline__ float gelu_exact(float x) {
    // exact-GELU via branch-free A&S 7.1.26 erf, |abs err| <= 1.5e-7
    // (far below one bf16 ulp of H -> output bits unchanged vs libm).
    const float z  = fabsf(x) * 0.7071067811865475f;
    const float t  = __builtin_amdgcn_rcpf(fmaf(0.3275911f, z, 1.0f));
    float p = fmaf(1.061405429f, t, -1.453152027f);
    p = fmaf(p, t, 1.421413741f);
    p = fmaf(p, t, -0.284496736f);
    p = fmaf(p, t, 0.254829592f);
    p = p * t;
    const float e  = __expf(-z * z);           // v_exp_f32 path
    const float er = fmaf(-p, e, 1.0f);        // erf(|z|) >= 0
    return 0.5f * x * (1.0f + copysignf(er, x));
}

// ---------------- prep: weights f32 -> bf16 in workspace --------------------
// Wc  [512][512]: rows 0-255 vW1, 256-511 pW1
// W2c [32][256]:  rows 0-5 vW2, 6-15 zero, 16-17 pW2, 18-31 zero
__global__ __launch_bounds__(256)
void prep_kernel(const float* __restrict__ vW1, const float* __restrict__ pW1,
                 const float* __restrict__ vW2, const float* __restrict__ pW2,
                 __hip_bfloat16* __restrict__ Wc, __hip_bfloat16* __restrict__ W2c)
{
    const int i = blockIdx.x * 256 + threadIdx.x;   // f32x4 chunk index
    if (i < 65536) {                                // W1: 262144 elems
        const int flat = i * 4;
        f32x4 v = (flat < 131072) ? *(const f32x4*)(vW1 + flat)
                                  : *(const f32x4*)(pW1 + flat - 131072);
        *(uint2*)(Wc + flat) = cvt4(v);
    } else if (i < 65536 + 2048) {                  // W2c: 8192 elems
        const int flat = (i - 65536) * 4;
        const int row = flat >> 8, col = flat & 255;
        f32x4 v = (f32x4){0.f, 0.f, 0.f, 0.f};
        if (row < 6)                      v = *(const f32x4*)(vW2 + row * HID + col);
        else if (row >= 16 && row < 18)   v = *(const f32x4*)(pW2 + (row - 16) * HID + col);
        *(uint2*)(W2c + flat) = cvt4(v);
    }
}

// ---------------- main ------------------------------------------------------
__global__ __launch_bounds__(256, 4)
void intention_heads_kernel(const float* __restrict__ X,
                            const int* __restrict__ ids,
                            const __hip_bfloat16* __restrict__ Wc,
                            const __hip_bfloat16* __restrict__ W2c,
                            const float* __restrict__ vb1,
                            const float* __restrict__ pb1,
                            const float* __restrict__ vb2,
                            const float* __restrict__ pb2,
                            float* __restrict__ out)
{
    // LDS: H only, 64x264 bf16 = 33792 B -> 4 blocks/CU.
    __shared__ __align__(16) __hip_bfloat16 H[64 * HSTR];

    // T1 bijective XCD swizzle (2048 % 8 == 0): head pair (2t,2t+1) and
    // neighboring token tiles land on one XCD -> X tile L2-resident.
    const int cpx = gridDim.x >> 3;
    const int bid = (blockIdx.x & 7) * cpx + (blockIdx.x >> 3);

    const int head = bid & 1;           // 0 = vehicle, 1 = pedestrian
    const int row0 = (bid >> 1) * 64;

    const int tid  = threadIdx.x;
    const int wave = tid >> 6;          // 0..3 -> hidden cols wave*64
    const int lane = tid & 63;
    const int quad = lane >> 4;
    const int l16  = lane & 15;
    const int wcol = wave * 64;

    // A-frag row pointers: lane reads rows i*16+l16, col chunk quad*8.
    // Per-iter offset is it*32 floats = it*128 B -> literal imm offsets.
    const float* Xr[4];
    #pragma unroll
    for (int i = 0; i < 4; ++i)
        Xr[i] = X + (long)(row0 + i * 16 + l16) * DIM + quad * 8;

    // B-frag row pointers (bf16 weights, row-major [n][k])
    const __hip_bfloat16* Wrow[4];
    #pragma unroll
    for (int j = 0; j < 4; ++j)
        Wrow[j] = Wc + (long)(head * 256 + wcol + j * 16 + l16) * DIM + quad * 8;

    f32x4 acc[4][4];
    #pragma unroll
    for (int i = 0; i < 4; ++i)
        #pragma unroll
        for (int j = 0; j < 4; ++j)
            acc[i][j] = (f32x4){0.f, 0.f, 0.f, 0.f};

    // ---- K loop: 16 iters, NO barriers, NO LDS — pure register dataflow.
    // Waves free-run; 16 waves/CU provide the latency hiding that the
    // lockstep barrier structure prevented (m233 mechanism).
    for (int it = 0; it < DIM / 32; ++it) {
        short8 bc[4];
        #pragma unroll
        for (int j = 0; j < 4; ++j)
            bc[j] = *(const short8*)(Wrow[j] + it * 32);

        short8 af[4];
        #pragma unroll
        for (int i = 0; i < 4; ++i) {
            f32x4 xa = *(const f32x4*)(Xr[i] + it * 32);
            f32x4 xb = *(const f32x4*)(Xr[i] + it * 32 + 4);
            union { short8 s; uint2 u[2]; } f;
            f.u[0] = cvt4(xa);
            f.u[1] = cvt4(xb);
            af[i] = f.s;
        }

        #pragma unroll
        for (int i = 0; i < 4; ++i)
            #pragma unroll
            for (int j = 0; j < 4; ++j)
                acc[i][j] = __builtin_amdgcn_mfma_f32_16x16x32_bf16(af[i], bc[j], acc[i][j], 0, 0, 0);
    }

    // ------------- bias + GELU, stage H tile (bf16) -----------------------
    const float* b1 = head ? pb1 : vb1;
    float b1v[4];
    #pragma unroll
    for (int j = 0; j < 4; ++j)
        b1v[j] = b1[wcol + j * 16 + l16];

    #pragma unroll
    for (int i = 0; i < 4; ++i) {
        #pragma unroll
        for (int j = 0; j < 4; ++j) {
            const int col = wcol + j * 16 + l16;
            #pragma unroll
            for (int rr = 0; rr < 4; ++rr) {
                const int row = i * 16 + quad * 4 + rr;
                H[row * HSTR + col] = bf16rne(gelu_exact(acc[i][j][rr] + b1v[j]));
            }
        }
    }
    __syncthreads();   // the ONE barrier: H handoff to layer 2

    // ------------- layer 2: H[64x256] @ W2^T (zero-padded to 16) ----------
    const float* b2 = head ? pb2 : vb2;
    const int nOut = head ? 2 : 6;

    f32x4 acc2 = (f32x4){0.f, 0.f, 0.f, 0.f};
    const int tokb = wave * 16;
    const short* hbase  = (const short*)&H[(tokb + l16) * HSTR + quad * 8];
    const __hip_bfloat16* w2base = W2c + (head * 16 + l16) * HID + quad * 8;
    #pragma unroll
    for (int k0 = 0; k0 < HID; k0 += 32) {
        short8 af    = *(const short8*)(hbase + k0);
        short8 bfrag = *(const short8*)(w2base + k0);   // zero rows pad n>=nOut
        acc2 = __builtin_amdgcn_mfma_f32_16x16x32_bf16(af, bfrag, acc2, 0, 0, 0);
    }

    // ------------- masked epilogue (f32 writes) ---------------------------
    const float b2v = (l16 < nOut) ? b2[l16] : 0.0f;

    #pragma unroll
    for (int rr = 0; rr < 4; ++rr) {
        const int t = row0 + tokb + quad * 4 + rr;
        const int type = ids[t];
        if (head == 0) {
            if (l16 == 0) {
                out[TOKENS * 6 + t] = (type == 1) ? 1.0f : 0.0f;
                out[TOKENS * 7 + t] = (type == 2) ? 1.0f : 0.0f;
            }
            if (l16 < 6) {
                if (type == 1)
                    out[t * 6 + l16] = acc2[rr] + b2v;
                else if (type != 2)
                    out[t * 6 + l16] = 0.0f;        // types 0,3 -> zeros
                // type==2 slots written by the pedestrian block
            }
        } else {
            if (l16 < 6 && type == 2)
                out[t * 6 + l16] = (l16 < 2) ? (acc2[rr] + b2v) : 0.0f;
        }
    }
}

extern "C" void kernel_launch(void* const* d_in, const int* in_sizes, int n_in,
                              void* d_out, int out_size, void* d_ws, size_t ws_size,
                              hipStream_t stream) {
    (void)n_in; (void)out_size; (void)ws_size;
    const float* X   = (const float*)d_in[0];
    const int*   ids = (const int*)d_in[1];
    const float* vW1 = (const float*)d_in[2];
    const float* vb1 = (const float*)d_in[3];
    const float* vW2 = (const float*)d_in[4];
    const float* vb2 = (const float*)d_in[5];
    const float* pW1 = (const float*)d_in[6];
    const float* pb1 = (const float*)d_in[7];
    const float* pW2 = (const float*)d_in[8];
    const float* pb2 = (const float*)d_in[9];
    float* out = (float*)d_out;

    // workspace: Wc [512*512] bf16 (512KB) ++ W2c [32*256] bf16 (16KB)
    __hip_bfloat16* Wc  = (__hip_bfloat16*)d_ws;
    __hip_bfloat16* W2c = Wc + 512 * DIM;

    hipLaunchKernelGGL(prep_kernel, dim3(264), dim3(256), 0, stream,
                       vW1, pW1, vW2, pW2, Wc, W2c);

    const int tokens = in_sizes[1];            // 65536
    const int grid   = (tokens / 64) * 2;      // token-tile x head

    hipLaunchKernelGGL(intention_heads_kernel, dim3(grid), dim3(256), 0, stream,
                       X, ids, Wc, W2c, vb1, pb1, vb2, pb2, out);
}

// Round 7
// 272.513 us; speedup vs baseline: 1.2995x; 1.2995x over previous
//
#include <hip/hip_runtime.h>
#include <hip/hip_bf16.h>
#include <math.h>

// IntentionHeads R15 = R13 + fragment-contiguous weight layout.
//   R14 (barrier-free, global A-frags): occupancy UP, conflicts gone, yet
//   1.67x SLOWER -> barriers exonerated; the MEMORY REQUEST STREAM binds.
//   Request model (~1 line/cy/CU): R13 = 4 blocks x (64 X-lines +
//   4 waves x 4 instr x 16 B-lines of 64B) = 1280 req/CU-iter ~= measured
//   1875cy/block-iter. R14 = 3072 req -> ~2x slower (measured 1.67x). R9 =
//   high req + half occupancy -> 241us. Model fits all rounds.
// R15 change (single variable): B requests halved.
//   - prep stores Wc in MFMA-fragment order: 16B chunk at
//     ((ntile*16 + it)*64 + lane)*16, lane = quad*16+l16. A wave's bc[j]
//     load becomes ONE contiguous 1KB-aligned read = 8 fully-used 128B
//     lines (was 16 half-used 64B lines, 16 rows @ 1KB stride).
//   - W2c likewise: chunk (ks*2+head)*1024 + lane*16.
//   - __launch_bounds__(256,4) + single B base pointer: VGPR back to <=64
//     (R13 slipped to 68 -> 3 blk/CU).
//   - Same per-lane values, same op order -> absmax bit-identical 0.015625.
//   - Everything else verbatim R13: triple-buffer X staging, lgkm-only
//     barriers, fast erf, XCD swizzle, H layout, epilogue.

#define TOKENS 65536
#define DIM    512
#define HID    256
#define ASTR   40    // X staging row stride in bf16 (32 + 8 pad, 16B mult)
#define ABUFB  5120  // one staging buffer: 64*ASTR*2 bytes
#define HSTR   264   // H row stride in bf16 (256 + 8 pad, 16B mult)

using short8 = __attribute__((ext_vector_type(8))) short;  // 8 x bf16
using f32x4  = __attribute__((ext_vector_type(4))) float;

// lgkm-only barrier: LDS producer/consumer ordering WITHOUT draining vmcnt
// (no global->LDS traffic exists; global loads are register-only).
#define BAR()                                                      \
    do {                                                           \
        __builtin_amdgcn_sched_barrier(0);                         \
        asm volatile("s_waitcnt lgkmcnt(0)" ::: "memory");         \
        __builtin_amdgcn_s_barrier();                              \
        __builtin_amdgcn_sched_barrier(0);                         \
    } while (0)

// packed RNE f32->bf16 pair (v_perm byte-pack)
__device__ __forceinline__ unsigned int pkrne(float a, float b) {
    unsigned int ua = __float_as_uint(a);
    unsigned int ub = __float_as_uint(b);
    ua += 0x7FFFu + ((ua >> 16) & 1u);
    ub += 0x7FFFu + ((ub >> 16) & 1u);
    return __builtin_amdgcn_perm(ub, ua, 0x07060302u);  // [ua.hi16, ub.hi16]
}

__device__ __forceinline__ uint2 cvt4(f32x4 v) {
    return make_uint2(pkrne(v[0], v[1]), pkrne(v[2], v[3]));
}

__device__ __forceinline__ __hip_bfloat16 bf16rne(float x) {
    unsigned int u = __float_as_uint(x);
    u += 0x7FFFu + ((u >> 16) & 1u);
    unsigned short hs = (unsigned short)(u >> 16);
    return *(__hip_bfloat16*)&hs;
}

__device__ __forceinline__ float gelu_exact(float x) {
    // exact-GELU via branch-free A&S 7.1.26 erf, |abs err| <= 1.5e-7
    // (far below one bf16 ulp of H -> output bits unchanged vs libm).
    const float z  = fabsf(x) * 0.7071067811865475f;
    const float t  = __builtin_amdgcn_rcpf(fmaf(0.3275911f, z, 1.0f));
    float p = fmaf(1.061405429f, t, -1.453152027f);
    p = fmaf(p, t, 1.421413741f);
    p = fmaf(p, t, -0.284496736f);
    p = fmaf(p, t, 0.254829592f);
    p = p * t;
    const float e  = __expf(-z * z);           // v_exp_f32 path
    const float er = fmaf(-p, e, 1.0f);        // erf(|z|) >= 0
    return 0.5f * x * (1.0f + copysignf(er, x));
}

// ---------------- prep: weights -> fragment-contiguous bf16 -----------------
// Wc  (512KB): 16B chunk c = ((nt*16 + it)*64 + lane), nt = head*16 + n/16,
//   lane = quad*16+l16 -> W1[head][ (nt&15)*16 + l16 ][ it*32 + quad*8 ..+7 ]
// W2c (32KB... 16KB used): chunk c = (ks*2+head)*64 + lane ->
//   W2[head][l16][ks*32 + quad*8 ..+7], zero when l16 >= nOut.
__global__ __launch_bounds__(256)
void prep_kernel(const float* __restrict__ vW1, const float* __restrict__ pW1,
                 const float* __restrict__ vW2, const float* __restrict__ pW2,
                 __hip_bfloat16* __restrict__ Wc, __hip_bfloat16* __restrict__ W2c)
{
    const int i = blockIdx.x * 256 + threadIdx.x;   // 16B chunk index
    if (i < 32768) {                                // W1: 512x512 bf16
        const int lane = i & 63;
        const int it   = (i >> 6) & 15;
        const int nt   = i >> 10;                   // 0..31
        const int head = nt >> 4;
        const int row  = (nt & 15) * 16 + (lane & 15);
        const int k    = it * 32 + (lane >> 4) * 8;
        const float* src = (head ? pW1 : vW1) + row * DIM + k;
        f32x4 a = *(const f32x4*)(src);
        f32x4 b = *(const f32x4*)(src + 4);
        uint2 lo = cvt4(a), hi = cvt4(b);
        *(uint4*)((char*)Wc + (long)i * 16) = make_uint4(lo.x, lo.y, hi.x, hi.y);
    } else if (i < 32768 + 1024) {                  // W2c: 16KB
        const int c    = i - 32768;
        const int lane = c & 63;
        const int rest = c >> 6;                    // 0..15
        const int head = rest & 1;
        const int ks   = rest >> 1;                 // 0..7
        const int l16  = lane & 15;
        const int quad = lane >> 4;
        const int nOut = head ? 2 : 6;
        uint4 o = make_uint4(0u, 0u, 0u, 0u);
        if (l16 < nOut) {
            const float* src = (head ? pW2 : vW2) + l16 * HID + ks * 32 + quad * 8;
            f32x4 a = *(const f32x4*)(src);
            f32x4 b = *(const f32x4*)(src + 4);
            uint2 lo = cvt4(a), hi = cvt4(b);
            o = make_uint4(lo.x, lo.y, hi.x, hi.y);
        }
        *(uint4*)((char*)W2c + (long)c * 16) = o;
    }
}

// ---------------- main ------------------------------------------------------
__global__ __launch_bounds__(256, 4)
void intention_heads_kernel(const float* __restrict__ X,
                            const int* __restrict__ ids,
                            const __hip_bfloat16* __restrict__ Wc,
                            const __hip_bfloat16* __restrict__ W2c,
                            const float* __restrict__ vb1,
                            const float* __restrict__ pb1,
                            const float* __restrict__ vb2,
                            const float* __restrict__ pb2,
                            float* __restrict__ out)
{
    // LDS union: X staging A0/A1/A2 (3 x 64x40 bf16 = 15.4KB) then H
    // 64x264 bf16 (33.8KB). 33792 B -> 4 blocks/CU.
    __shared__ __align__(16) unsigned char smem[64 * HSTR * 2];
    __hip_bfloat16* H = (__hip_bfloat16*)smem;

    // T1 bijective XCD swizzle (2048 % 8 == 0): head pair (2t,2t+1) and
    // neighboring token tiles land on one XCD -> X shared in its L2.
    const int cpx = gridDim.x >> 3;
    const int bid = (blockIdx.x & 7) * cpx + (blockIdx.x >> 3);

    const int head = bid & 1;           // 0 = vehicle, 1 = pedestrian
    const int row0 = (bid >> 1) * 64;

    const int tid  = threadIdx.x;
    const int wave = tid >> 6;          // 0..3 -> hidden cols wave*64
    const int lane = tid & 63;
    const int quad = lane >> 4;
    const int l16  = lane & 15;
    const int wcol = wave * 64;

    // X staging: thread owns f32x4 at col q*4 of rows r2 and r2+32
    const int q  = tid & 7;
    const int r2 = tid >> 3;            // 0..31
    const float* Xs = X + (long)(row0 + r2) * DIM + q * 4;

    // B frags, fragment-contiguous: wave's chunk = contiguous 1KB per (j,it)
    const char* Bq = (const char*)Wc
                   + (long)(head * 16 + wave * 4) * 16384 + (long)lane * 16;

    f32x4 acc[4][4];
    #pragma unroll
    for (int i = 0; i < 4; ++i)
        #pragma unroll
        for (int j = 0; j < 4; ++j)
            acc[i][j] = (f32x4){0.f, 0.f, 0.f, 0.f};

    // ---- prologue: load tiles 0,1 raw; stage tile 0; rotate ----
    f32x4 ga0 = *(const f32x4*)(Xs);
    f32x4 ga1 = *(const f32x4*)(Xs + 32 * DIM);
    f32x4 gb0 = *(const f32x4*)(Xs + 32);
    f32x4 gb1 = *(const f32x4*)(Xs + 32 * DIM + 32);
    {
        __hip_bfloat16* A = (__hip_bfloat16*)smem;   // buffer 0
        *(uint2*)&A[r2 * ASTR + q * 4]        = cvt4(ga0);
        *(uint2*)&A[(r2 + 32) * ASTR + q * 4] = cvt4(ga1);
    }
    BAR();
    ga0 = gb0; ga1 = gb1;               // ga now holds tile 1 raw

    // ---- K loop: 16 iters, BK=32, triple buffer, deep prefetch ----
    #pragma unroll
    for (int it = 0; it < DIM / 32; ++it) {
        __hip_bfloat16* cur = (__hip_bfloat16*)(smem + (it % 3) * ABUFB);
        __hip_bfloat16* nxt = (__hip_bfloat16*)(smem + ((it + 1) % 3) * ABUFB);

        // issue tile it+2 raw loads (consumed bottom of iter it+1)
        if (it < 14) {
            gb0 = *(const f32x4*)(Xs + (it + 2) * 32);
            gb1 = *(const f32x4*)(Xs + 32 * DIM + (it + 2) * 32);
        }

        // this iter's B frags: 4 contiguous 1KB wave-reads (8 full lines ea)
        short8 bc[4];
        #pragma unroll
        for (int j = 0; j < 4; ++j)
            bc[j] = *(const short8*)(Bq + j * 16384 + it * 1024);

        short8 af[4];
        #pragma unroll
        for (int i = 0; i < 4; ++i)
            af[i] = *(const short8*)&cur[(i * 16 + l16) * ASTR + quad * 8];

        #pragma unroll
        for (int i = 0; i < 4; ++i)
            #pragma unroll
            for (int j = 0; j < 4; ++j)
                acc[i][j] = __builtin_amdgcn_mfma_f32_16x16x32_bf16(af[i], bc[j], acc[i][j], 0, 0, 0);

        // convert+stage tile it+1 (raw data in flight since iter it-1 top)
        if (it < 15) {
            *(uint2*)&nxt[r2 * ASTR + q * 4]        = cvt4(ga0);
            *(uint2*)&nxt[(r2 + 32) * ASTR + q * 4] = cvt4(ga1);
        }
        BAR();
        ga0 = gb0; ga1 = gb1;
    }

    // ------------- bias + GELU, stage H tile (bf16) -----------------------
    const float* b1 = head ? pb1 : vb1;
    float b1v[4];
    #pragma unroll
    for (int j = 0; j < 4; ++j)
        b1v[j] = b1[wcol + j * 16 + l16];

    #pragma unroll
    for (int i = 0; i < 4; ++i) {
        #pragma unroll
        for (int j = 0; j < 4; ++j) {
            const int col = wcol + j * 16 + l16;
            #pragma unroll
            for (int rr = 0; rr < 4; ++rr) {
                const int row = i * 16 + quad * 4 + rr;
                H[row * HSTR + col] = bf16rne(gelu_exact(acc[i][j][rr] + b1v[j]));
            }
        }
    }
    BAR();

    // ------------- layer 2: H[64x256] @ W2^T (frag-contiguous W2c) --------
    const float* b2 = head ? pb2 : vb2;
    const int nOut = head ? 2 : 6;

    f32x4 acc2 = (f32x4){0.f, 0.f, 0.f, 0.f};
    const int tokb = wave * 16;
    const short* hbase = (const short*)&H[(tokb + l16) * HSTR + quad * 8];
    const char*  w2q   = (const char*)W2c + head * 1024 + (long)lane * 16;
    #pragma unroll
    for (int ks = 0; ks < 8; ++ks) {
        short8 af    = *(const short8*)(hbase + ks * 32);
        short8 bfrag = *(const short8*)(w2q + ks * 2048);  // zero-padded rows
        acc2 = __builtin_amdgcn_mfma_f32_16x16x32_bf16(af, bfrag, acc2, 0, 0, 0);
    }

    // ------------- masked epilogue (f32 writes) ---------------------------
    const float b2v = (l16 < nOut) ? b2[l16] : 0.0f;

    #pragma unroll
    for (int rr = 0; rr < 4; ++rr) {
        const int t = row0 + tokb + quad * 4 + rr;
        const int type = ids[t];
        if (head == 0) {
            if (l16 == 0) {
                out[TOKENS * 6 + t] = (type == 1) ? 1.0f : 0.0f;
                out[TOKENS * 7 + t] = (type == 2) ? 1.0f : 0.0f;
            }
            if (l16 < 6) {
                if (type == 1)
                    out[t * 6 + l16] = acc2[rr] + b2v;
                else if (type != 2)
                    out[t * 6 + l16] = 0.0f;        // types 0,3 -> zeros
                // type==2 slots written by the pedestrian block
            }
        } else {
            if (l16 < 6 && type == 2)
                out[t * 6 + l16] = (l16 < 2) ? (acc2[rr] + b2v) : 0.0f;
        }
    }
}

extern "C" void kernel_launch(void* const* d_in, const int* in_sizes, int n_in,
                              void* d_out, int out_size, void* d_ws, size_t ws_size,
                              hipStream_t stream) {
    (void)n_in; (void)out_size; (void)ws_size;
    const float* X   = (const float*)d_in[0];
    const int*   ids = (const int*)d_in[1];
    const float* vW1 = (const float*)d_in[2];
    const float* vb1 = (const float*)d_in[3];
    const float* vW2 = (const float*)d_in[4];
    const float* vb2 = (const float*)d_in[5];
    const float* pW1 = (const float*)d_in[6];
    const float* pb1 = (const float*)d_in[7];
    const float* pW2 = (const float*)d_in[8];
    const float* pb2 = (const float*)d_in[9];
    float* out = (float*)d_out;

    // workspace: Wc [512*512] bf16 (512KB) ++ W2c [16*1024] bf16 (16KB... 
    // chunk space = 1024 chunks * 16B = 16KB)
    __hip_bfloat16* Wc  = (__hip_bfloat16*)d_ws;
    __hip_bfloat16* W2c = Wc + 512 * DIM;

    hipLaunchKernelGGL(prep_kernel, dim3(132), dim3(256), 0, stream,
                       vW1, pW1, vW2, pW2, Wc, W2c);

    const int tokens = in_sizes[1];            // 65536
    const int grid   = (tokens / 64) * 2;      // token-tile x head

    hipLaunchKernelGGL(intention_heads_kernel, dim3(grid), dim3(256), 0, stream,
                       X, ids, Wc, W2c, vb1, pb1, vb2, pb2, out);
}

// Round 8
// 253.877 us; speedup vs baseline: 1.3948x; 1.0734x over previous
//
#include <hip/hip_runtime.h>
#include <hip/hip_bf16.h>
#include <math.h>

// IntentionHeads R16 = R15 content, 8 thin waves/block (pure TLP test).
//   R15 post-mortem: WRITE_SIZE 2->77MB + FETCH 69->105MB = scratch spill
//   (launch_bounds (256,4) forced 64 VGPR, code needed ~68; 77MB/8192
//   waves = 9.4KB/wave = 2-3 slots x 16 iters). Frag-B layout gain was
//   eaten by the spill tax; time flat at 121us.
//   Ledger: only resident-wave count ever moved time BOTH ways (R10 -25%
//   occupancy = +47% time; R9 -50% = +85%). All variants sat at 16
//   waves/CU (64 VGPR + 64 AGPR = 128 = 4/SIMD quantum). Test the other
//   side of the occupancy curve.
// R16 change: 512-thr blocks, 8 waves x (64 tok x 32 cols), acc[4][2]
//   (32 AGPR), bc[2] (8 VGPR) -> ~78 regs -> 6 waves/SIMD = 24 waves/CU
//   (75% theoretical, was 50%). Grid/tile/X-traffic/B-traffic/requests/
//   LDS/staging/numerics IDENTICAL to R15. launch_bounds(512,6) caps 85
//   regs (needed ~78) -> spill-free. Layer 2 + epilogue on waves 0-3
//   exactly as before; waves 4-7 exit after the H barrier.
//   Keeps: frag-contiguous Wc/W2c, fast erf, lgkm-only BAR, XCD swizzle.

#define TOKENS 65536
#define DIM    512
#define HID    256
#define ASTR   40    // X staging row stride in bf16 (32 + 8 pad, 16B mult)
#define HSTR   264   // H row stride in bf16 (256 + 8 pad, 16B mult)

using short8 = __attribute__((ext_vector_type(8))) short;  // 8 x bf16
using f32x4  = __attribute__((ext_vector_type(4))) float;

// lgkm-only barrier: LDS producer/consumer ordering WITHOUT draining vmcnt
// (no global->LDS traffic exists; global loads are register-only).
#define BAR()                                                      \
    do {                                                           \
        __builtin_amdgcn_sched_barrier(0);                         \
        asm volatile("s_waitcnt lgkmcnt(0)" ::: "memory");         \
        __builtin_amdgcn_s_barrier();                              \
        __builtin_amdgcn_sched_barrier(0);                         \
    } while (0)

// packed RNE f32->bf16 pair (v_perm byte-pack)
__device__ __forceinline__ unsigned int pkrne(float a, float b) {
    unsigned int ua = __float_as_uint(a);
    unsigned int ub = __float_as_uint(b);
    ua += 0x7FFFu + ((ua >> 16) & 1u);
    ub += 0x7FFFu + ((ub >> 16) & 1u);
    return __builtin_amdgcn_perm(ub, ua, 0x07060302u);  // [ua.hi16, ub.hi16]
}

__device__ __forceinline__ uint2 cvt4(f32x4 v) {
    return make_uint2(pkrne(v[0], v[1]), pkrne(v[2], v[3]));
}

__device__ __forceinline__ __hip_bfloat16 bf16rne(float x) {
    unsigned int u = __float_as_uint(x);
    u += 0x7FFFu + ((u >> 16) & 1u);
    unsigned short hs = (unsigned short)(u >> 16);
    return *(__hip_bfloat16*)&hs;
}

__device__ __forceinline__ float gelu_exact(float x) {
    // exact-GELU via branch-free A&S 7.1.26 erf, |abs err| <= 1.5e-7
    // (far below one bf16 ulp of H -> output bits unchanged vs libm).
    const float z  = fabsf(x) * 0.7071067811865475f;
    const float t  = __builtin_amdgcn_rcpf(fmaf(0.3275911f, z, 1.0f));
    float p = fmaf(1.061405429f, t, -1.453152027f);
    p = fmaf(p, t, 1.421413741f);
    p = fmaf(p, t, -0.284496736f);
    p = fmaf(p, t, 0.254829592f);
    p = p * t;
    const float e  = __expf(-z * z);           // v_exp_f32 path
    const float er = fmaf(-p, e, 1.0f);        // erf(|z|) >= 0
    return 0.5f * x * (1.0f + copysignf(er, x));
}

// ---------------- prep: weights -> fragment-contiguous bf16 -----------------
// Wc  (512KB): 16B chunk c = ((nt*16 + it)*64 + lane), nt = head*16 + n/16,
//   lane = quad*16+l16 -> W1[head][ (nt&15)*16 + l16 ][ it*32 + quad*8 ..+7 ]
// W2c (16KB): chunk c = (ks*2+head)*64 + lane ->
//   W2[head][l16][ks*32 + quad*8 ..+7], zero when l16 >= nOut.
__global__ __launch_bounds__(256)
void prep_kernel(const float* __restrict__ vW1, const float* __restrict__ pW1,
                 const float* __restrict__ vW2, const float* __restrict__ pW2,
                 __hip_bfloat16* __restrict__ Wc, __hip_bfloat16* __restrict__ W2c)
{
    const int i = blockIdx.x * 256 + threadIdx.x;   // 16B chunk index
    if (i < 32768) {                                // W1: 512x512 bf16
        const int lane = i & 63;
        const int it   = (i >> 6) & 15;
        const int nt   = i >> 10;                   // 0..31
        const int head = nt >> 4;
        const int row  = (nt & 15) * 16 + (lane & 15);
        const int k    = it * 32 + (lane >> 4) * 8;
        const float* src = (head ? pW1 : vW1) + row * DIM + k;
        f32x4 a = *(const f32x4*)(src);
        f32x4 b = *(const f32x4*)(src + 4);
        uint2 lo = cvt4(a), hi = cvt4(b);
        *(uint4*)((char*)Wc + (long)i * 16) = make_uint4(lo.x, lo.y, hi.x, hi.y);
    } else if (i < 32768 + 1024) {                  // W2c: 16KB
        const int c    = i - 32768;
        const int lane = c & 63;
        const int rest = c >> 6;                    // 0..15
        const int head = rest & 1;
        const int ks   = rest >> 1;                 // 0..7
        const int l16  = lane & 15;
        const int quad = lane >> 4;
        const int nOut = head ? 2 : 6;
        uint4 o = make_uint4(0u, 0u, 0u, 0u);
        if (l16 < nOut) {
            const float* src = (head ? pW2 : vW2) + l16 * HID + ks * 32 + quad * 8;
            f32x4 a = *(const f32x4*)(src);
            f32x4 b = *(const f32x4*)(src + 4);
            uint2 lo = cvt4(a), hi = cvt4(b);
            o = make_uint4(lo.x, lo.y, hi.x, hi.y);
        }
        *(uint4*)((char*)W2c + (long)c * 16) = o;
    }
}

// ---------------- main ------------------------------------------------------
__global__ __launch_bounds__(512, 6)
void intention_heads_kernel(const float* __restrict__ X,
                            const int* __restrict__ ids,
                            const __hip_bfloat16* __restrict__ Wc,
                            const __hip_bfloat16* __restrict__ W2c,
                            const float* __restrict__ vb1,
                            const float* __restrict__ pb1,
                            const float* __restrict__ vb2,
                            const float* __restrict__ pb2,
                            float* __restrict__ out)
{
    // LDS union: X staging A0/A1 (2 x 64x40 bf16 = 10.2KB) then H
    // 64x264 bf16 (33.8KB). 33792 B; 3 blocks/CU (reg-bound) -> 101KB LDS.
    __shared__ __align__(16) unsigned char smem[64 * HSTR * 2];
    __hip_bfloat16* H = (__hip_bfloat16*)smem;

    // T1 bijective XCD swizzle (2048 % 8 == 0): head pair (2t,2t+1) and
    // neighboring token tiles land on one XCD -> X shared in its L2.
    const int cpx = gridDim.x >> 3;
    const int bid = (blockIdx.x & 7) * cpx + (blockIdx.x >> 3);

    const int head = bid & 1;           // 0 = vehicle, 1 = pedestrian
    const int row0 = (bid >> 1) * 64;

    const int tid  = threadIdx.x;
    const int wave = tid >> 6;          // 0..7 -> cols wave*32
    const int lane = tid & 63;
    const int quad = lane >> 4;
    const int l16  = lane & 15;
    const int wcol = wave * 32;

    // X staging: 512 threads, thread owns ONE f32x4: row r, col chunk q
    const int q = tid & 7;
    const int r = tid >> 3;             // 0..63
    const float* Xs = X + (long)(row0 + r) * DIM + q * 4;

    // B frags, fragment-contiguous: wave's (j,it) chunk = contiguous 1KB.
    // ntile for col wcol+j*16 is head*16 + wave*2 + j.
    const char* Bq = (const char*)Wc
                   + (long)(head * 16 + wave * 2) * 16384 + (long)lane * 16;

    f32x4 acc[4][2];
    #pragma unroll
    for (int i = 0; i < 4; ++i)
        #pragma unroll
        for (int j = 0; j < 2; ++j)
            acc[i][j] = (f32x4){0.f, 0.f, 0.f, 0.f};

    // ---- prologue: stage tile 0 ----
    f32x4 ga = *(const f32x4*)(Xs);
    {
        __hip_bfloat16* A = (__hip_bfloat16*)smem;   // buffer 0
        *(uint2*)&A[r * ASTR + q * 4] = cvt4(ga);
    }
    BAR();

    // ---- K loop: 16 iters, BK=32, double buffer, depth-1 prefetch ----
    #pragma unroll
    for (int it = 0; it < DIM / 32; ++it) {
        __hip_bfloat16* cur = (__hip_bfloat16*)(smem + (it & 1) * 5120);
        __hip_bfloat16* nxt = (__hip_bfloat16*)(smem + ((it + 1) & 1) * 5120);

        // issue tile it+1 raw load (consumed at this iter's bottom)
        if (it < 15)
            ga = *(const f32x4*)(Xs + (it + 1) * 32);

        // this iter's B frags: 2 contiguous 1KB wave-reads (8 full lines ea)
        short8 bc[2];
        #pragma unroll
        for (int j = 0; j < 2; ++j)
            bc[j] = *(const short8*)(Bq + j * 16384 + it * 1024);

        short8 af[4];
        #pragma unroll
        for (int i = 0; i < 4; ++i)
            af[i] = *(const short8*)&cur[(i * 16 + l16) * ASTR + quad * 8];

        #pragma unroll
        for (int i = 0; i < 4; ++i)
            #pragma unroll
            for (int j = 0; j < 2; ++j)
                acc[i][j] = __builtin_amdgcn_mfma_f32_16x16x32_bf16(af[i], bc[j], acc[i][j], 0, 0, 0);

        // convert+stage tile it+1
        if (it < 15)
            *(uint2*)&nxt[r * ASTR + q * 4] = cvt4(ga);
        BAR();
    }

    // ------------- bias + GELU, stage H tile (bf16) -----------------------
    const float* b1 = head ? pb1 : vb1;
    float b1v[2];
    #pragma unroll
    for (int j = 0; j < 2; ++j)
        b1v[j] = b1[wcol + j * 16 + l16];

    #pragma unroll
    for (int i = 0; i < 4; ++i) {
        #pragma unroll
        for (int j = 0; j < 2; ++j) {
            const int col = wcol + j * 16 + l16;
            #pragma unroll
            for (int rr = 0; rr < 4; ++rr) {
                const int row = i * 16 + quad * 4 + rr;
                H[row * HSTR + col] = bf16rne(gelu_exact(acc[i][j][rr] + b1v[j]));
            }
        }
    }
    BAR();

    // ------------- layer 2 (waves 0-3): H[64x256] @ W2^T ------------------
    if (wave < 4) {
        const float* b2 = head ? pb2 : vb2;
        const int nOut = head ? 2 : 6;

        f32x4 acc2 = (f32x4){0.f, 0.f, 0.f, 0.f};
        const int tokb = wave * 16;
        const short* hbase = (const short*)&H[(tokb + l16) * HSTR + quad * 8];
        const char*  w2q   = (const char*)W2c + head * 1024 + (long)lane * 16;
        #pragma unroll
        for (int ks = 0; ks < 8; ++ks) {
            short8 af    = *(const short8*)(hbase + ks * 32);
            short8 bfrag = *(const short8*)(w2q + ks * 2048);  // zero-padded
            acc2 = __builtin_amdgcn_mfma_f32_16x16x32_bf16(af, bfrag, acc2, 0, 0, 0);
        }

        // ------------- masked epilogue (f32 writes) -----------------------
        const float b2v = (l16 < nOut) ? b2[l16] : 0.0f;

        #pragma unroll
        for (int rr = 0; rr < 4; ++rr) {
            const int t = row0 + tokb + quad * 4 + rr;
            const int type = ids[t];
            if (head == 0) {
                if (l16 == 0) {
                    out[TOKENS * 6 + t] = (type == 1) ? 1.0f : 0.0f;
                    out[TOKENS * 7 + t] = (type == 2) ? 1.0f : 0.0f;
                }
                if (l16 < 6) {
                    if (type == 1)
                        out[t * 6 + l16] = acc2[rr] + b2v;
                    else if (type != 2)
                        out[t * 6 + l16] = 0.0f;        // types 0,3 -> zeros
                    // type==2 slots written by the pedestrian block
                }
            } else {
                if (l16 < 6 && type == 2)
                    out[t * 6 + l16] = (l16 < 2) ? (acc2[rr] + b2v) : 0.0f;
            }
        }
    }
}

extern "C" void kernel_launch(void* const* d_in, const int* in_sizes, int n_in,
                              void* d_out, int out_size, void* d_ws, size_t ws_size,
                              hipStream_t stream) {
    (void)n_in; (void)out_size; (void)ws_size;
    const float* X   = (const float*)d_in[0];
    const int*   ids = (const int*)d_in[1];
    const float* vW1 = (const float*)d_in[2];
    const float* vb1 = (const float*)d_in[3];
    const float* vW2 = (const float*)d_in[4];
    const float* vb2 = (const float*)d_in[5];
    const float* pW1 = (const float*)d_in[6];
    const float* pb1 = (const float*)d_in[7];
    const float* pW2 = (const float*)d_in[8];
    const float* pb2 = (const float*)d_in[9];
    float* out = (float*)d_out;

    // workspace: Wc [512*512] bf16 (512KB) ++ W2c (16KB)
    __hip_bfloat16* Wc  = (__hip_bfloat16*)d_ws;
    __hip_bfloat16* W2c = Wc + 512 * DIM;

    hipLaunchKernelGGL(prep_kernel, dim3(132), dim3(256), 0, stream,
                       vW1, pW1, vW2, pW2, Wc, W2c);

    const int tokens = in_sizes[1];            // 65536
    const int grid   = (tokens / 64) * 2;      // token-tile x head

    hipLaunchKernelGGL(intention_heads_kernel, dim3(grid), dim3(512), 0, stream,
                       X, ids, Wc, W2c, vb1, pb1, vb2, pb2, out);
}